// Round 3
// baseline (346.412 us; speedup 1.0000x reference)
//
#include <hip/hip_runtime.h>

#define NB 4096   // B
#define NS 200    // S
#define NP 8      // P
#define NF 64     // F

#define RB 5      // batch rows per block
#define LPS 50    // lane-slices per row (RB*LPS = 250 active threads)
#define IT 4      // items per thread (LPS*IT = NS exactly)

__global__ __launch_bounds__(256) void cf_kernel(
    const int*   __restrict__ user,
    const int*   __restrict__ items,
    const float* __restrict__ user_factors,   // [N_USERS][P][F] fp32
    const float* __restrict__ item_factors,   // [N_ITEMS][F]    fp32
    float* __restrict__ out_pred,             // [B][S]          fp32
    float* __restrict__ out_scores)           // [B][S][P]       fp32
{
    // per-row u, transposed [f][p] so 8 personas for one f are one float4 pair
    __shared__ float u_lds[RB][NF * NP];      // 10 KB

    const int tid  = threadIdx.x;
    const int b0   = blockIdx.x * RB;
    const int rows = min(RB, NB - b0);

    // ---- stage user factors: rows*512 floats, coalesced read, transposed write ----
    for (int e = tid; e < rows * (NP * NF); e += 256) {
        int g = e >> 9;            // /512
        int q = e & 511;
        int uid = user[b0 + g];
        float w = user_factors[(size_t)uid * (NP * NF) + q];
        int p = q >> 6, f = q & 63;
        u_lds[g][f * NP + p] = w;
    }
    __syncthreads();

    const int g = tid / LPS;
    const int l = tid - g * LPS;
    if (g >= rows) return;         // also kills tid 250..255
    const int b = b0 + g;
    const float* __restrict__ ug = u_lds[g];

    // gather base pointers for this thread's 4 items
    const float4* vp[IT];
    int svec[IT];
    #pragma unroll
    for (int k = 0; k < IT; ++k) {
        int s = l + LPS * k;
        svec[k] = s;
        int idx = items[b * NS + s];
        vp[k] = (const float4*)(item_factors + (size_t)idx * NF);
    }

    float acc[IT][NP];
    #pragma unroll
    for (int k = 0; k < IT; ++k)
        #pragma unroll
        for (int p = 0; p < NP; ++p) acc[k][p] = 0.f;

    #pragma unroll
    for (int c = 0; c < NF / 8; ++c) {
        float4 v[IT][2];
        #pragma unroll
        for (int k = 0; k < IT; ++k) {   // 8 independent scattered loads in flight
            v[k][0] = vp[k][2 * c];
            v[k][1] = vp[k][2 * c + 1];
        }
        #pragma unroll
        for (int j = 0; j < 8; ++j) {
            // <=2 distinct addresses per wave (2 u-tables) -> conflict-free b128
            const float4* up = (const float4*)&ug[(c * 8 + j) * NP];
            float4 ua = up[0];
            float4 ub = up[1];
            #pragma unroll
            for (int k = 0; k < IT; ++k) {
                float vv = ((const float*)&v[k][0])[j];  // folds to component at compile time
                acc[k][0] += vv * ua.x;  acc[k][1] += vv * ua.y;
                acc[k][2] += vv * ua.z;  acc[k][3] += vv * ua.w;
                acc[k][4] += vv * ub.x;  acc[k][5] += vv * ub.y;
                acc[k][6] += vv * ub.z;  acc[k][7] += vv * ub.w;
            }
        }
    }

    // ---- per-item softmax over P + pred ----
    #pragma unroll
    for (int k = 0; k < IT; ++k) {
        float m = acc[k][0];
        #pragma unroll
        for (int p = 1; p < NP; ++p) m = fmaxf(m, acc[k][p]);
        float e[NP], sum = 0.f;
        #pragma unroll
        for (int p = 0; p < NP; ++p) { e[p] = __expf(acc[k][p] - m); sum += e[p]; }
        float inv = 1.f / sum;

        float sc[NP], pred = 0.f;
        #pragma unroll
        for (int p = 0; p < NP; ++p) {
            sc[p] = e[p] * inv;
            pred += sc[p] * acc[k][p];
        }

        const int s = svec[k];
        out_pred[b * NS + s] = pred;
        float4* op = (float4*)(out_scores + (size_t)(b * NS + s) * NP);
        op[0] = make_float4(sc[0], sc[1], sc[2], sc[3]);
        op[1] = make_float4(sc[4], sc[5], sc[6], sc[7]);
    }
}

extern "C" void kernel_launch(void* const* d_in, const int* in_sizes, int n_in,
                              void* d_out, int out_size, void* d_ws, size_t ws_size,
                              hipStream_t stream) {
    const int*   user         = (const int*)d_in[0];
    const int*   items        = (const int*)d_in[1];
    const float* user_factors = (const float*)d_in[2];
    const float* item_factors = (const float*)d_in[3];

    float* out_pred   = (float*)d_out;
    float* out_scores = out_pred + (size_t)NB * NS;   // outputs concatenated: pred, scores

    const int grid = (NB + RB - 1) / RB;   // 820
    cf_kernel<<<grid, 256, 0, stream>>>(user, items, user_factors, item_factors,
                                        out_pred, out_scores);
}